// Round 6
// baseline (54.852 us; speedup 1.0000x reference)
//
#include <hip/hip_runtime.h>
#include <math.h>

#define L_TOTAL 49152
#define NBLK 768
#define ROWS_PER_BLK 64   // L_TOTAL / NBLK
#define ROWS_PER_WAVE 16  // 4 waves per block
#define NWGROUPS (NBLK * 4)   // 3072 wave-groups of 16 rows
#define SCR_STRIDE 520        // floats per row slot: 512 + 8 pad (bank spread)

__device__ __forceinline__ float4 f4add(float4 a, float4 b) {
  return make_float4(a.x + b.x, a.y + b.y, a.z + b.z, a.w + b.w);
}

// Emulate np.float32 -> float16 (RNE, incl. subnormals) -> float32.
// Input x is positive and finite (x = 1/(l+1) <= 1).
__device__ __forceinline__ float fp16_roundtrip_pos(float x) {
  unsigned u = __float_as_uint(x);
  int e = (int)((u >> 23) & 0xffu) - 127;
  unsigned m = (u & 0x7fffffu) | 0x800000u;          // 24-bit mantissa
  int shift = (e >= -14) ? 13 : (13 + (-14 - e));    // extra shift for subnormals
  if (shift >= 25) return 0.0f;                      // underflow
  unsigned keep = m >> shift;
  unsigned rem = m & ((1u << shift) - 1u);
  unsigned halfbit = 1u << (shift - 1);
  if (rem > halfbit || (rem == halfbit && (keep & 1u))) keep++;
  return ldexpf((float)keep, e + shift - 23);
}

// Kernel A: per wave, 16 rows. For each 4-row batch:
//   - each lane computes 8 partials (2 batches x 4 cols) over its 16 f-values
//     and writes them to wave-private LDS scratch (2x ds_write_b128, no
//     butterfly at all);
//   - transpose-reduce: lane (rhat, chat, h) sums 32 scratch floats + 1
//     shfl_xor -> full g[row][chat];
//   - 2-level shfl_up scan over the 4 rows + running carry -> wave-level
//     inclusive scan, stored to gf; wave total -> ppw.
// Kernel boundary provides cross-block coherence (coop grid.sync is broken
// in this harness, R2/R3).
__global__ __launch_bounds__(256, 3) void gpart_kernel(
    const int* __restrict__ ex, const float4* __restrict__ win4,
    const float4* __restrict__ pos4, const float4* __restrict__ wf4,
    float* __restrict__ gf, float* __restrict__ ppwf) {
  __shared__ float scratch[4][4 * SCR_STRIDE];

  const int lane = threadIdx.x & 63;
  const int wv = threadIdx.x >> 6;
  float* scr = scratch[wv];
  const int rowBase = blockIdx.x * ROWS_PER_BLK + wv * ROWS_PER_WAVE;

  // W_in / W_final fragments in registers, reused for all 16 rows.
  float4 win[4];
  float4 wf[4][4];
#pragma unroll
  for (int j = 0; j < 4; ++j) {
    const int fi = j * 64 + lane;  // float4 index into the 1024-long f axis
    win[j] = win4[fi];
#pragma unroll
    for (int k = 0; k < 4; ++k) wf[j][k] = wf4[fi * 4 + k];
  }

  const int rhat = lane >> 4;        // 0..3  (row within batch)
  const int chat = (lane >> 1) & 7;  // 0..7  (b*4 + c)
  const int h = lane & 1;            // 0..1  (src-lane half)

  float carry = 0.0f;

  for (int batch = 0; batch < 4; ++batch) {
#pragma unroll
    for (int r = 0; r < 4; ++r) {
      const int l = rowBase + batch * 4 + r;
      const float s0 = (float)ex[l] - 3.0f;          // ((e/4*2-1)*2-1) == e-3
      const float s1 = (float)ex[L_TOTAL + l] - 3.0f;
      float4 a0 = make_float4(0.f, 0.f, 0.f, 0.f);
      float4 a1 = make_float4(0.f, 0.f, 0.f, 0.f);
#pragma unroll
      for (int j = 0; j < 4; ++j) {
        const float4 p = pos4[(size_t)l * 256 + j * 64 + lane];
        const float pc[4] = {p.x, p.y, p.z, p.w};
        const float wc[4] = {win[j].x, win[j].y, win[j].z, win[j].w};
#pragma unroll
        for (int k = 0; k < 4; ++k) {
          const float t0 = fmaxf(fmaf(s0, wc[k], pc[k]), 0.0f);
          const float t1 = fmaxf(fmaf(s1, wc[k], pc[k]), 0.0f);
          const float4 w = wf[j][k];
          a0.x = fmaf(t0, w.x, a0.x); a0.y = fmaf(t0, w.y, a0.y);
          a0.z = fmaf(t0, w.z, a0.z); a0.w = fmaf(t0, w.w, a0.w);
          a1.x = fmaf(t1, w.x, a1.x); a1.y = fmaf(t1, w.y, a1.y);
          a1.z = fmaf(t1, w.z, a1.z); a1.w = fmaf(t1, w.w, a1.w);
        }
      }
      // Dump partials -- no per-row reduction.
      float* dst = &scr[r * SCR_STRIDE + lane * 8];
      *(float4*)(dst) = a0;
      *(float4*)(dst + 4) = a1;
    }

    // Transpose-reduce: column chat of batch-row rhat over 64 src lanes.
    const float* src = &scr[rhat * SCR_STRIDE + h * 32 * 8 + chat];
    float s = 0.0f;
#pragma unroll
    for (int i = 0; i < 32; ++i) s += src[i * 8];
    s += __shfl_xor(s, 1);  // combine the two 32-src halves

    // Inclusive scan over the 4 batch rows (row stride = 16 lanes).
    {
      float u = __shfl_up(s, 16);
      if (rhat >= 1) s += u;
      u = __shfl_up(s, 32);
      if (rhat >= 2) s += u;
    }
    const float vout = s + carry;
    carry = __shfl(vout, 48 + (lane & 15));  // row-3 value for same (chat,h)

    if (h == 0) {
      const int row = rowBase + batch * 4 + rhat;
      gf[(size_t)(chat >> 2) * L_TOTAL * 4 + (size_t)row * 4 + (chat & 3)] =
          vout;
    }
  }

  // Per-wave totals (8 floats) for cross-wave/cross-block offsets.
  if (h == 0 && rhat == 0) {
    const int wg = blockIdx.x * 4 + wv;
    ppwf[(size_t)(chat >> 2) * NWGROUPS * 4 + (size_t)wg * 4 + (chat & 3)] =
        carry;
  }
}

// Kernel B: out[b,row] = (g[b,row] + sum of preceding wave-group totals)
//           * fp16(1/(row+1)) + b_final.  One wave per batch, 64 rows/block.
__global__ __launch_bounds__(128, 8) void finish_kernel(
    const float4* __restrict__ g4, const float4* __restrict__ ppw,
    const float* __restrict__ bfin, float4* __restrict__ out4) {
  const int tid = threadIdx.x;
  const int bb = tid >> 6;   // batch 0/1
  const int i = tid & 63;    // row within block
  const int bid = blockIdx.x;
  const int wgBase = bid * 4;

  // Cooperative sum of ppw[bb][j] for j < wgBase (wave-wide, L2-hot).
  float4 q = make_float4(0.f, 0.f, 0.f, 0.f);
  for (int j = i; j < wgBase; j += 64) q = f4add(q, ppw[bb * NWGROUPS + j]);
#pragma unroll
  for (int off = 32; off > 0; off >>= 1) {
    q.x += __shfl_xor(q.x, off); q.y += __shfl_xor(q.y, off);
    q.z += __shfl_xor(q.z, off); q.w += __shfl_xor(q.w, off);
  }
  // Intra-block wave-group adjustment (0..3 extra float4s).
  const int gsub = i >> 4;
  for (int k = 0; k < gsub; ++k)
    q = f4add(q, ppw[bb * NWGROUPS + wgBase + k]);

  const int row = bid * ROWS_PER_BLK + i;
  const float4 v = f4add(g4[(size_t)bb * L_TOTAL + row], q);
  const float factor = fp16_roundtrip_pos(1.0f / (float)(row + 1));
  float4 o;
  o.x = fmaf(v.x, factor, bfin[0]);
  o.y = fmaf(v.y, factor, bfin[1]);
  o.z = fmaf(v.z, factor, bfin[2]);
  o.w = fmaf(v.w, factor, bfin[3]);
  out4[(size_t)bb * L_TOTAL + row] = o;
}

extern "C" void kernel_launch(void* const* d_in, const int* in_sizes, int n_in,
                              void* d_out, int out_size, void* d_ws, size_t ws_size,
                              hipStream_t stream) {
  const int* ex = (const int*)d_in[0];            // example [2,128,128,3] int32
  const float4* win4 = (const float4*)d_in[1];    // W_in [1,1024]
  const float4* pos4 = (const float4*)d_in[2];    // pos_enc [49152,1024]
  const float4* wf4 = (const float4*)d_in[3];     // W_final [1024,4]
  const float* bfin = (const float*)d_in[4];      // b_final [4]
  float4* out4 = (float4*)d_out;

  float* gf = (float*)d_ws;                       // [2][L_TOTAL][4] floats
  float* ppwf = gf + (size_t)2 * L_TOTAL * 4;     // [2][NWGROUPS][4] floats

  gpart_kernel<<<NBLK, 256, 0, stream>>>(ex, win4, pos4, wf4, gf, ppwf);
  finish_kernel<<<NBLK, 128, 0, stream>>>((const float4*)gf,
                                          (const float4*)ppwf, bfin, out4);
}

// Round 7
// 48.773 us; speedup vs baseline: 1.1246x; 1.1246x over previous
//
#include <hip/hip_runtime.h>
#include <math.h>

#define L_TOTAL 49152
#define NBLK 768
#define ROWS_PER_BLK 64
#define NCHUNK 32          // 1024 f / 32 f per chunk (32 f = 128 B = 1 line/row)

__device__ __forceinline__ float4 f4add(float4 a, float4 b) {
  return make_float4(a.x + b.x, a.y + b.y, a.z + b.z, a.w + b.w);
}

// Emulate np.float32 -> float16 (RNE, incl. subnormals) -> float32.
// Input x is positive and finite (x = 1/(l+1) <= 1).
__device__ __forceinline__ float fp16_roundtrip_pos(float x) {
  unsigned u = __float_as_uint(x);
  int e = (int)((u >> 23) & 0xffu) - 127;
  unsigned m = (u & 0x7fffffu) | 0x800000u;          // 24-bit mantissa
  int shift = (e >= -14) ? 13 : (13 + (-14 - e));    // extra shift for subnormals
  if (shift >= 25) return 0.0f;                      // underflow
  unsigned keep = m >> shift;
  unsigned rem = m & ((1u << shift) - 1u);
  unsigned halfbit = 1u << (shift - 1);
  if (rem > halfbit || (rem == halfbit && (keep & 1u))) keep++;
  return ldexpf((float)keep, e + shift - 23);
}

// Kernel A (row-per-lane): block = 64 rows, 256 threads.
// Wave w covers rows [w*16, w*16+16); lane = seg*16 + r16: lane accumulates
// row (w*16+r16) over f-segment seg (8 floats per 32-f chunk). pos_enc is
// staged chunk-by-chunk into a double-buffered LDS tile [64][36 floats]
// (stride 36 -> 8 lanes/bank-quad on both b128 writes and reads = conflict-
// free). Reduction over f is lane-local FMA; cross-seg = 2 shfl_xor levels;
// then a 4-level shfl_up scan over 16 rows + tiny cross-wave LDS scan gives
// block-scanned g. No per-row butterfly anywhere.
__global__ __launch_bounds__(256, 3) void gpart_kernel(
    const int* __restrict__ ex, const float4* __restrict__ win4,
    const float4* __restrict__ pos4, const float4* __restrict__ wf4,
    float4* __restrict__ gbuf, float4* __restrict__ pp) {
  __shared__ float4 tile[2][ROWS_PER_BLK][9];   // 8 data float4 + 1 pad
  __shared__ float4 wtot[2][4];

  const int tid = threadIdx.x;
  const int lane = tid & 63;
  const int wv = tid >> 6;
  const int rowBase = blockIdx.x * ROWS_PER_BLK;

  const int r_st = tid >> 2;        // staging row 0..63
  const int q_st = tid & 3;         // staging float4-slot 0..3

  const int seg = lane >> 4;        // 0..3 f-segment
  const int r16 = lane & 15;        // row within wave
  const int myrow = wv * 16 + r16;  // block-local row
  const int grow = rowBase + myrow; // global row

  const float s0 = (float)ex[grow] - 3.0f;            // ((e/4*2-1)*2-1)==e-3
  const float s1 = (float)ex[L_TOTAL + grow] - 3.0f;

  float4 a0 = make_float4(0.f, 0.f, 0.f, 0.f);
  float4 a1 = make_float4(0.f, 0.f, 0.f, 0.f);

  const size_t prow = (size_t)(rowBase + r_st) * 256;  // pos4 row base

  // prologue: stage chunk 0 into buf 0
  tile[0][r_st][q_st]     = pos4[prow + q_st];
  tile[0][r_st][q_st + 4] = pos4[prow + q_st + 4];
  __syncthreads();

  for (int c = 0; c < NCHUNK; ++c) {
    // stage chunk c+1 into the other buffer (overlaps with compute of c)
    if (c + 1 < NCHUNK) {
      const int f4n = (c + 1) * 8;
      tile[(c + 1) & 1][r_st][q_st]     = pos4[prow + f4n + q_st];
      tile[(c + 1) & 1][r_st][q_st + 4] = pos4[prow + f4n + q_st + 4];
    }
    // compute chunk c: this lane's 8 f-values of its row
    const int f4b = c * 8 + seg * 2;
    const float4 p0 = tile[c & 1][myrow][seg * 2];
    const float4 p1 = tile[c & 1][myrow][seg * 2 + 1];
    const float4 w0 = win4[f4b];
    const float4 w1 = win4[f4b + 1];
    const float pe[8] = {p0.x, p0.y, p0.z, p0.w, p1.x, p1.y, p1.z, p1.w};
    const float we[8] = {w0.x, w0.y, w0.z, w0.w, w1.x, w1.y, w1.z, w1.w};
#pragma unroll
    for (int e = 0; e < 8; ++e) {
      const float4 wf = wf4[f4b * 4 + e];            // L1-broadcast
      const float t0 = fmaxf(fmaf(s0, we[e], pe[e]), 0.0f);
      const float t1 = fmaxf(fmaf(s1, we[e], pe[e]), 0.0f);
      a0.x = fmaf(t0, wf.x, a0.x); a0.y = fmaf(t0, wf.y, a0.y);
      a0.z = fmaf(t0, wf.z, a0.z); a0.w = fmaf(t0, wf.w, a0.w);
      a1.x = fmaf(t1, wf.x, a1.x); a1.y = fmaf(t1, wf.y, a1.y);
      a1.z = fmaf(t1, wf.z, a1.z); a1.w = fmaf(t1, wf.w, a1.w);
    }
    __syncthreads();
  }

  // cross-seg reduction (segments live 16 lanes apart): masks 16, 32
#define REDUCE8(MASK)                                                   \
  a0.x += __shfl_xor(a0.x, MASK); a0.y += __shfl_xor(a0.y, MASK);       \
  a0.z += __shfl_xor(a0.z, MASK); a0.w += __shfl_xor(a0.w, MASK);       \
  a1.x += __shfl_xor(a1.x, MASK); a1.y += __shfl_xor(a1.y, MASK);       \
  a1.z += __shfl_xor(a1.z, MASK); a1.w += __shfl_xor(a1.w, MASK);
  REDUCE8(16)
  REDUCE8(32)
#undef REDUCE8

  // inclusive scan over the 16 rows of this wave (value replicated per seg)
#pragma unroll
  for (int d = 1; d < 16; d <<= 1) {
    const float u0 = __shfl_up(a0.x, d), u1 = __shfl_up(a0.y, d);
    const float u2 = __shfl_up(a0.z, d), u3 = __shfl_up(a0.w, d);
    const float u4 = __shfl_up(a1.x, d), u5 = __shfl_up(a1.y, d);
    const float u6 = __shfl_up(a1.z, d), u7 = __shfl_up(a1.w, d);
    if (r16 >= d) {
      a0.x += u0; a0.y += u1; a0.z += u2; a0.w += u3;
      a1.x += u4; a1.y += u5; a1.z += u6; a1.w += u7;
    }
  }

  // wave totals (value at r16==15) -> LDS for cross-wave offsets
  float4 t0, t1;
  t0.x = __shfl(a0.x, 15); t0.y = __shfl(a0.y, 15);
  t0.z = __shfl(a0.z, 15); t0.w = __shfl(a0.w, 15);
  t1.x = __shfl(a1.x, 15); t1.y = __shfl(a1.y, 15);
  t1.z = __shfl(a1.z, 15); t1.w = __shfl(a1.w, 15);
  if (lane == 0) { wtot[0][wv] = t0; wtot[1][wv] = t1; }
  __syncthreads();
  float4 o0 = make_float4(0.f, 0.f, 0.f, 0.f);
  float4 o1 = make_float4(0.f, 0.f, 0.f, 0.f);
  for (int j = 0; j < wv; ++j) {
    o0 = f4add(o0, wtot[0][j]);
    o1 = f4add(o1, wtot[1][j]);
  }
  a0 = f4add(a0, o0);
  a1 = f4add(a1, o1);

  if (seg == 0) {           // one copy per row writes block-scanned g
    gbuf[grow] = a0;
    gbuf[L_TOTAL + grow] = a1;
  }
  if (tid == 255) {         // wv=3, r16=15 -> block-inclusive total
    pp[blockIdx.x] = a0;
    pp[NBLK + blockIdx.x] = a1;
  }
}

// Kernel B: out[b,row] = (g_scanned[b,row] + sum of preceding blocks' totals)
//           * fp16(1/(row+1)) + b_final. pp is L2-hot (24 KB).
__global__ __launch_bounds__(128, 8) void finish_kernel(
    const float4* __restrict__ gbuf, const float4* __restrict__ pp,
    const float* __restrict__ bfin, float4* __restrict__ out4) {
  const int tid = threadIdx.x;
  const int bb = tid >> 6;   // batch 0/1
  const int i = tid & 63;    // row within block
  const int bid = blockIdx.x;

  // offset = sum of pp[bb][j] for j < bid (wave-strided + butterfly)
  float4 q = make_float4(0.f, 0.f, 0.f, 0.f);
  for (int j = i; j < bid; j += 64) q = f4add(q, pp[bb * NBLK + j]);
#pragma unroll
  for (int off = 32; off > 0; off >>= 1) {
    q.x += __shfl_xor(q.x, off); q.y += __shfl_xor(q.y, off);
    q.z += __shfl_xor(q.z, off); q.w += __shfl_xor(q.w, off);
  }

  const int row = bid * ROWS_PER_BLK + i;
  const float4 v = f4add(gbuf[(size_t)bb * L_TOTAL + row], q);
  const float factor = fp16_roundtrip_pos(1.0f / (float)(row + 1));
  float4 o;
  o.x = fmaf(v.x, factor, bfin[0]);
  o.y = fmaf(v.y, factor, bfin[1]);
  o.z = fmaf(v.z, factor, bfin[2]);
  o.w = fmaf(v.w, factor, bfin[3]);
  out4[(size_t)bb * L_TOTAL + row] = o;
}

extern "C" void kernel_launch(void* const* d_in, const int* in_sizes, int n_in,
                              void* d_out, int out_size, void* d_ws, size_t ws_size,
                              hipStream_t stream) {
  const int* ex = (const int*)d_in[0];            // example [2,128,128,3] int32
  const float4* win4 = (const float4*)d_in[1];    // W_in [1,1024]
  const float4* pos4 = (const float4*)d_in[2];    // pos_enc [49152,1024]
  const float4* wf4 = (const float4*)d_in[3];     // W_final [1024,4]
  const float* bfin = (const float*)d_in[4];      // b_final [4]
  float4* out4 = (float4*)d_out;

  float4* gbuf = (float4*)d_ws;                   // [2][L_TOTAL] float4
  float4* pp = gbuf + (size_t)2 * L_TOTAL;        // [2][NBLK] float4

  gpart_kernel<<<NBLK, 256, 0, stream>>>(ex, win4, pos4, wf4, gbuf, pp);
  finish_kernel<<<NBLK, 128, 0, stream>>>(gbuf, pp, bfin, out4);
}

// Round 8
// 48.036 us; speedup vs baseline: 1.1419x; 1.0153x over previous
//
#include <hip/hip_runtime.h>
#include <math.h>

#define L_TOTAL 49152
#define NBLK 768
#define ROWS_PER_BLK 64
#define NCHUNK 32          // 1024 f / 32 f per chunk (32 f = 128 B = 1 line/row)

__device__ __forceinline__ float4 f4add(float4 a, float4 b) {
  return make_float4(a.x + b.x, a.y + b.y, a.z + b.z, a.w + b.w);
}

// Emulate np.float32 -> float16 (RNE, incl. subnormals) -> float32.
// Input x is positive and finite (x = 1/(l+1) <= 1).
__device__ __forceinline__ float fp16_roundtrip_pos(float x) {
  unsigned u = __float_as_uint(x);
  int e = (int)((u >> 23) & 0xffu) - 127;
  unsigned m = (u & 0x7fffffu) | 0x800000u;          // 24-bit mantissa
  int shift = (e >= -14) ? 13 : (13 + (-14 - e));    // extra shift for subnormals
  if (shift >= 25) return 0.0f;                      // underflow
  unsigned keep = m >> shift;
  unsigned rem = m & ((1u << shift) - 1u);
  unsigned halfbit = 1u << (shift - 1);
  if (rem > halfbit || (rem == halfbit && (keep & 1u))) keep++;
  return ldexpf((float)keep, e + shift - 23);
}

// Kernel A (row-per-lane, 2-deep staged pipeline):
// iter c: ds_write chunk c+1 (regs, loaded one full phase ago) -> buf[(c+1)&1];
//         issue global loads chunk c+2 -> regs;
//         compute chunk c from buf[c&1];
//         barrier (waits only on LDS writes, never on HBM latency).
// Global requests therefore stay in flight across every barrier.
__global__ __launch_bounds__(256, 3) void gpart_kernel(
    const int* __restrict__ ex, const float4* __restrict__ win4,
    const float4* __restrict__ pos4, const float4* __restrict__ wf4,
    float4* __restrict__ gbuf, float4* __restrict__ pp) {
  __shared__ float4 tile[2][ROWS_PER_BLK][9];   // 8 data float4 + 1 pad
  __shared__ float4 wtot[2][4];

  const int tid = threadIdx.x;
  const int lane = tid & 63;
  const int wv = tid >> 6;
  const int rowBase = blockIdx.x * ROWS_PER_BLK;

  const int r_st = tid >> 2;        // staging row 0..63
  const int q_st = tid & 3;         // staging float4-slot 0..3

  const int seg = lane >> 4;        // 0..3 f-segment
  const int r16 = lane & 15;        // row within wave
  const int myrow = wv * 16 + r16;  // block-local row
  const int grow = rowBase + myrow; // global row

  const float s0 = (float)ex[grow] - 3.0f;            // ((e/4*2-1)*2-1)==e-3
  const float s1 = (float)ex[L_TOTAL + grow] - 3.0f;

  float4 a0 = make_float4(0.f, 0.f, 0.f, 0.f);
  float4 a1 = make_float4(0.f, 0.f, 0.f, 0.f);

  const size_t prow = (size_t)(rowBase + r_st) * 256;  // pos4 row base

  // prologue: chunk 0 straight to LDS; chunk 1 into staging regs
  tile[0][r_st][q_st]     = pos4[prow + q_st];
  tile[0][r_st][q_st + 4] = pos4[prow + q_st + 4];
  float4 stA = pos4[prow + 8 + q_st];
  float4 stB = pos4[prow + 8 + q_st + 4];
  __syncthreads();

  for (int c = 0; c < NCHUNK; ++c) {
    // (1) ds_write chunk c+1 from regs (its loads are a full phase old)
    if (c + 1 < NCHUNK) {
      tile[(c + 1) & 1][r_st][q_st]     = stA;
      tile[(c + 1) & 1][r_st][q_st + 4] = stB;
    }
    // (2) issue global loads for chunk c+2 (stay in flight through barrier)
    if (c + 2 < NCHUNK) {
      const int f4n = (c + 2) * 8;
      stA = pos4[prow + f4n + q_st];
      stB = pos4[prow + f4n + q_st + 4];
    }
    // (3) compute chunk c: this lane's 8 f-values of its row
    const int f4b = c * 8 + seg * 2;
    const float4 p0 = tile[c & 1][myrow][seg * 2];
    const float4 p1 = tile[c & 1][myrow][seg * 2 + 1];
    const float4 w0 = win4[f4b];
    const float4 w1 = win4[f4b + 1];
    const float pe[8] = {p0.x, p0.y, p0.z, p0.w, p1.x, p1.y, p1.z, p1.w};
    const float we[8] = {w0.x, w0.y, w0.z, w0.w, w1.x, w1.y, w1.z, w1.w};
#pragma unroll
    for (int e = 0; e < 8; ++e) {
      const float4 wf = wf4[f4b * 4 + e];            // L1-broadcast
      const float t0 = fmaxf(fmaf(s0, we[e], pe[e]), 0.0f);
      const float t1 = fmaxf(fmaf(s1, we[e], pe[e]), 0.0f);
      a0.x = fmaf(t0, wf.x, a0.x); a0.y = fmaf(t0, wf.y, a0.y);
      a0.z = fmaf(t0, wf.z, a0.z); a0.w = fmaf(t0, wf.w, a0.w);
      a1.x = fmaf(t1, wf.x, a1.x); a1.y = fmaf(t1, wf.y, a1.y);
      a1.z = fmaf(t1, wf.z, a1.z); a1.w = fmaf(t1, wf.w, a1.w);
    }
    // (4) barrier: waits on ds_writes (lgkm), not on the c+2 global loads
    __syncthreads();
  }

  // cross-seg reduction (segments live 16 lanes apart): masks 16, 32
#define REDUCE8(MASK)                                                   \
  a0.x += __shfl_xor(a0.x, MASK); a0.y += __shfl_xor(a0.y, MASK);       \
  a0.z += __shfl_xor(a0.z, MASK); a0.w += __shfl_xor(a0.w, MASK);       \
  a1.x += __shfl_xor(a1.x, MASK); a1.y += __shfl_xor(a1.y, MASK);       \
  a1.z += __shfl_xor(a1.z, MASK); a1.w += __shfl_xor(a1.w, MASK);
  REDUCE8(16)
  REDUCE8(32)
#undef REDUCE8

  // inclusive scan over the 16 rows of this wave (value replicated per seg)
#pragma unroll
  for (int d = 1; d < 16; d <<= 1) {
    const float u0 = __shfl_up(a0.x, d), u1 = __shfl_up(a0.y, d);
    const float u2 = __shfl_up(a0.z, d), u3 = __shfl_up(a0.w, d);
    const float u4 = __shfl_up(a1.x, d), u5 = __shfl_up(a1.y, d);
    const float u6 = __shfl_up(a1.z, d), u7 = __shfl_up(a1.w, d);
    if (r16 >= d) {
      a0.x += u0; a0.y += u1; a0.z += u2; a0.w += u3;
      a1.x += u4; a1.y += u5; a1.z += u6; a1.w += u7;
    }
  }

  // wave totals (value at r16==15) -> LDS for cross-wave offsets
  float4 t0, t1;
  t0.x = __shfl(a0.x, 15); t0.y = __shfl(a0.y, 15);
  t0.z = __shfl(a0.z, 15); t0.w = __shfl(a0.w, 15);
  t1.x = __shfl(a1.x, 15); t1.y = __shfl(a1.y, 15);
  t1.z = __shfl(a1.z, 15); t1.w = __shfl(a1.w, 15);
  if (lane == 0) { wtot[0][wv] = t0; wtot[1][wv] = t1; }
  __syncthreads();
  float4 o0 = make_float4(0.f, 0.f, 0.f, 0.f);
  float4 o1 = make_float4(0.f, 0.f, 0.f, 0.f);
  for (int j = 0; j < wv; ++j) {
    o0 = f4add(o0, wtot[0][j]);
    o1 = f4add(o1, wtot[1][j]);
  }
  a0 = f4add(a0, o0);
  a1 = f4add(a1, o1);

  if (seg == 0) {           // one copy per row writes block-scanned g
    gbuf[grow] = a0;
    gbuf[L_TOTAL + grow] = a1;
  }
  if (tid == 255) {         // wv=3, r16=15 -> block-inclusive total
    pp[blockIdx.x] = a0;
    pp[NBLK + blockIdx.x] = a1;
  }
}

// Kernel B: out[b,row] = (g_scanned[b,row] + sum of preceding blocks' totals)
//           * fp16(1/(row+1)) + b_final. pp is L2-hot (24 KB).
__global__ __launch_bounds__(128, 8) void finish_kernel(
    const float4* __restrict__ gbuf, const float4* __restrict__ pp,
    const float* __restrict__ bfin, float4* __restrict__ out4) {
  const int tid = threadIdx.x;
  const int bb = tid >> 6;   // batch 0/1
  const int i = tid & 63;    // row within block
  const int bid = blockIdx.x;

  // offset = sum of pp[bb][j] for j < bid (wave-strided + butterfly)
  float4 q = make_float4(0.f, 0.f, 0.f, 0.f);
  for (int j = i; j < bid; j += 64) q = f4add(q, pp[bb * NBLK + j]);
#pragma unroll
  for (int off = 32; off > 0; off >>= 1) {
    q.x += __shfl_xor(q.x, off); q.y += __shfl_xor(q.y, off);
    q.z += __shfl_xor(q.z, off); q.w += __shfl_xor(q.w, off);
  }

  const int row = bid * ROWS_PER_BLK + i;
  const float4 v = f4add(gbuf[(size_t)bb * L_TOTAL + row], q);
  const float factor = fp16_roundtrip_pos(1.0f / (float)(row + 1));
  float4 o;
  o.x = fmaf(v.x, factor, bfin[0]);
  o.y = fmaf(v.y, factor, bfin[1]);
  o.z = fmaf(v.z, factor, bfin[2]);
  o.w = fmaf(v.w, factor, bfin[3]);
  out4[(size_t)bb * L_TOTAL + row] = o;
}

extern "C" void kernel_launch(void* const* d_in, const int* in_sizes, int n_in,
                              void* d_out, int out_size, void* d_ws, size_t ws_size,
                              hipStream_t stream) {
  const int* ex = (const int*)d_in[0];            // example [2,128,128,3] int32
  const float4* win4 = (const float4*)d_in[1];    // W_in [1,1024]
  const float4* pos4 = (const float4*)d_in[2];    // pos_enc [49152,1024]
  const float4* wf4 = (const float4*)d_in[3];     // W_final [1024,4]
  const float* bfin = (const float*)d_in[4];      // b_final [4]
  float4* out4 = (float4*)d_out;

  float4* gbuf = (float4*)d_ws;                   // [2][L_TOTAL] float4
  float4* pp = gbuf + (size_t)2 * L_TOTAL;        // [2][NBLK] float4

  gpart_kernel<<<NBLK, 256, 0, stream>>>(ex, win4, pos4, wf4, gbuf, pp);
  finish_kernel<<<NBLK, 128, 0, stream>>>(gbuf, pp, bfin, out4);
}